// Round 4
// baseline (170.967 us; speedup 1.0000x reference)
//
#include <hip/hip_runtime.h>
#include <math.h>

// CAP = (300+400+900)/300/1000*300400 = 1602.13333...; thresh = 0.2*CAP
#define THRESH 320.42666666666668f
#define T_LEN 96

// 4 threads per day; each thread loads 6+6 float4 (a quarter-day from each
// input). Grid is exactly num_days*4/256 blocks (200000*4 = 3125*256).
__global__ __launch_bounds__(256) void day_score_kernel(
    const float* __restrict__ pred, const float* __restrict__ tru,
    float* __restrict__ out, int num_days, float inv_days)
{
    __shared__ float wsum[4];
    const int tid = blockIdx.x * 256 + threadIdx.x;
    const int day = tid >> 2;   // 4 threads per day
    const int k   = tid & 3;    // quarter within day
    const bool valid = (day < num_days);
    const int day_c = valid ? day : (num_days - 1);

    const float4* tp = (const float4*)tru  + (long long)day_c * 24 + k * 6;
    const float4* pp = (const float4*)pred + (long long)day_c * 24 + k * 6;

    // ---- Phase 1: issue ALL 12 loads ----
    float4 t0 = tp[0], t1 = tp[1], t2 = tp[2], t3 = tp[3], t4 = tp[4], t5 = tp[5];
    float4 p0 = pp[0], p1 = pp[1], p2 = pp[2], p3 = pp[3], p4 = pp[4], p5 = pp[5];
    // Opaque memory clobber: no load may be sunk past this point, so all 12
    // loads are issued back-to-back and stay in flight together.
    asm volatile("" ::: "memory");

    // ---- Phase 2: compute (denom >= 320 so fast rcp is safe, ~1e-6 rel) ----
    float s = 0.0f;
#define ACC(tv, pv)                                                             \
    {                                                                           \
        float r;                                                                \
        r = (tv.x - pv.x) * __builtin_amdgcn_rcpf(fmaxf(tv.x, THRESH)); s += r*r; \
        r = (tv.y - pv.y) * __builtin_amdgcn_rcpf(fmaxf(tv.y, THRESH)); s += r*r; \
        r = (tv.z - pv.z) * __builtin_amdgcn_rcpf(fmaxf(tv.z, THRESH)); s += r*r; \
        r = (tv.w - pv.w) * __builtin_amdgcn_rcpf(fmaxf(tv.w, THRESH)); s += r*r; \
    }
    ACC(t0, p0) ACC(t1, p1) ACC(t2, p2) ACC(t3, p3) ACC(t4, p4) ACC(t5, p5)
#undef ACC

    // ---- Phase 3: 4-lane group -> full day sum (groups are lane-aligned) ----
    s += __shfl_xor(s, 1);
    s += __shfl_xor(s, 2);
    float score = valid ? (1.0f - sqrtf(s * (1.0f / (float)T_LEN))) * 100.0f : 0.0f;
    // all 4 lanes of a day hold the same score; butterfly over stages 4..32
    // sums lanes {0,4,8,...,60} -> each of the wave's 16 days counted once
    score += __shfl_xor(score, 4);
    score += __shfl_xor(score, 8);
    score += __shfl_xor(score, 16);
    score += __shfl_xor(score, 32);

    const int lane = threadIdx.x & 63;
    const int wave = threadIdx.x >> 6;
    if (lane == 0) wsum[wave] = score;
    __syncthreads();
    if (threadIdx.x == 0) {
        const float blk = (wsum[0] + wsum[1]) + (wsum[2] + wsum[3]);
        atomicAdd(out, blk * inv_days);   // 3125 atomics total (as in R2/R3)
    }
}

extern "C" void kernel_launch(void* const* d_in, const int* in_sizes, int n_in,
                              void* d_out, int out_size, void* d_ws, size_t ws_size,
                              hipStream_t stream) {
    (void)n_in; (void)d_ws; (void)ws_size;
    const float* pred = (const float*)d_in[0];   // setup_inputs: {"pred": ..., "true": ...}
    const float* tru  = (const float*)d_in[1];
    float* out = (float*)d_out;

    const int n        = in_sizes[1];
    const int num_days = n / T_LEN;
    const int nblocks  = (num_days * 4 + 255) / 256;   // 3125 for 200000 days

    hipMemsetAsync(out, 0, (size_t)out_size * sizeof(float), stream);
    day_score_kernel<<<nblocks, 256, 0, stream>>>(pred, tru, out, num_days,
                                                  1.0f / (float)num_days);
}

// Round 5
// 169.280 us; speedup vs baseline: 1.0100x; 1.0100x over previous
//
#include <hip/hip_runtime.h>
#include <math.h>

// CAP = (300+400+900)/300/1000*300400 = 1602.13333...; thresh = 0.2*CAP
#define THRESH 320.42666666666668f
#define T_LEN 96
#define SLAB_DAYS 64                 // days per block-iteration (256 thr = 4/day)
#define NBLOCKS 512                  // persistent grid, ~2 blocks/CU

__global__ __launch_bounds__(256) void day_score_kernel(
    const float* __restrict__ pred, const float* __restrict__ tru,
    float* __restrict__ out, int num_days, float scale)
{
    __shared__ float wsum[4];
    const int g = threadIdx.x >> 2;          // day within slab, 0..63
    const int k = threadIdx.x & 3;           // quarter within day, 0..3
    const int n_slabs = (num_days + SLAB_DAYS - 1) / SLAB_DAYS;

    const float4* tru4  = (const float4*)tru;
    const float4* pred4 = (const float4*)pred;

    float acc = 0.0f;   // sum of day-scores (each day counted on all 4 lanes)

    // Persistent grid-stride loop over 64-day slabs: loads for slab i+1 are
    // independent of slab i's compute -> compiler software-pipelines, keeping
    // loads continuously in flight (the m13/m146 streaming recipe).
    for (int slab = blockIdx.x; slab < n_slabs; slab += gridDim.x) {
        const int day = slab * SLAB_DAYS + g;
        if (day >= num_days) break;          // (200000 % 64 == 0: never taken)
        const float4* tp = tru4  + (size_t)day * 24 + k * 6;
        const float4* pp = pred4 + (size_t)day * 24 + k * 6;

        float s = 0.0f;
#pragma unroll
        for (int j = 0; j < 6; ++j) {
            const float4 tv = tp[j];
            const float4 pv = pp[j];
            float r;
            r = (tv.x - pv.x) * __builtin_amdgcn_rcpf(fmaxf(tv.x, THRESH)); s += r * r;
            r = (tv.y - pv.y) * __builtin_amdgcn_rcpf(fmaxf(tv.y, THRESH)); s += r * r;
            r = (tv.z - pv.z) * __builtin_amdgcn_rcpf(fmaxf(tv.z, THRESH)); s += r * r;
            r = (tv.w - pv.w) * __builtin_amdgcn_rcpf(fmaxf(tv.w, THRESH)); s += r * r;
        }
        // combine the 4 quarter-day partials (lanes of a day are 4-aligned)
        s += __shfl_xor(s, 1);
        s += __shfl_xor(s, 2);
        // all 4 lanes hold the full day sum; all accumulate (fixed by x0.25)
        acc += (1.0f - sqrtf(s * (1.0f / (float)T_LEN))) * 100.0f;
    }

    // wave butterfly: sums all 64 lanes (each day counted 4x -> scale has 0.25)
    acc += __shfl_xor(acc, 1);
    acc += __shfl_xor(acc, 2);
    acc += __shfl_xor(acc, 4);
    acc += __shfl_xor(acc, 8);
    acc += __shfl_xor(acc, 16);
    acc += __shfl_xor(acc, 32);

    const int lane = threadIdx.x & 63;
    const int wave = threadIdx.x >> 6;
    if (lane == 0) wsum[wave] = acc;
    __syncthreads();
    if (threadIdx.x == 0) {
        const float blk = (wsum[0] + wsum[1]) + (wsum[2] + wsum[3]);
        atomicAdd(out, blk * scale);         // NBLOCKS atomics total
    }
}

extern "C" void kernel_launch(void* const* d_in, const int* in_sizes, int n_in,
                              void* d_out, int out_size, void* d_ws, size_t ws_size,
                              hipStream_t stream) {
    (void)n_in; (void)d_ws; (void)ws_size;
    const float* pred = (const float*)d_in[0];   // setup_inputs: {"pred": ..., "true": ...}
    const float* tru  = (const float*)d_in[1];
    float* out = (float*)d_out;

    const int n        = in_sizes[1];
    const int num_days = n / T_LEN;
    const float scale  = 0.25f / (float)num_days;   // 0.25: day counted on 4 lanes

    hipMemsetAsync(out, 0, (size_t)out_size * sizeof(float), stream);
    day_score_kernel<<<NBLOCKS, 256, 0, stream>>>(pred, tru, out, num_days, scale);
}